// Round 1
// baseline (65.126 us; speedup 1.0000x reference)
//
#include <hip/hip_runtime.h>
#include <math.h>

#define DIM 3072
#define SEQ 8192

__device__ __forceinline__ float silu_f(float v) {
    return v / (1.0f + __expf(-v));
}

// One block per output index i (3 consecutive W rows: shift, scale, gate).
// silu(emb) staged in LDS once per block; W streamed as float4 (coalesced).
__global__ __launch_bounds__(256) void gemv3_kernel(
    const float* __restrict__ emb, const float* __restrict__ W,
    const float* __restrict__ b, float* __restrict__ shift,
    float* __restrict__ scale, float* __restrict__ gate)
{
    __shared__ float s[DIM];
    __shared__ float red[3][4];
    const int t = threadIdx.x;
    const float4* emb4 = (const float4*)emb;
    float4* s4 = (float4*)s;

    #pragma unroll
    for (int k = 0; k < 3; ++k) {
        int i = t + k * 256;                 // float4 index < 768
        float4 v = emb4[i];
        v.x = silu_f(v.x); v.y = silu_f(v.y);
        v.z = silu_f(v.z); v.w = silu_f(v.w);
        s4[i] = v;
    }
    __syncthreads();

    const int i0 = blockIdx.x;               // 0..DIM-1
    float acc[3] = {0.f, 0.f, 0.f};
    #pragma unroll
    for (int r = 0; r < 3; ++r) {
        const float4* w4 = (const float4*)(W + (size_t)(3 * i0 + r) * DIM);
        #pragma unroll
        for (int k = 0; k < 3; ++k) {
            int i = t + k * 256;
            float4 w = w4[i];
            float4 v = s4[i];
            acc[r] += w.x * v.x + w.y * v.y + w.z * v.z + w.w * v.w;
        }
    }

    // block reduce: 64-lane shuffle, then 4 partials via LDS
    #pragma unroll
    for (int off = 32; off > 0; off >>= 1) {
        #pragma unroll
        for (int r = 0; r < 3; ++r) acc[r] += __shfl_down(acc[r], off, 64);
    }
    const int wave = t >> 6;
    if ((t & 63) == 0) {
        #pragma unroll
        for (int r = 0; r < 3; ++r) red[r][wave] = acc[r];
    }
    __syncthreads();
    if (t == 0) {
        float v0 = red[0][0] + red[0][1] + red[0][2] + red[0][3] + b[3 * i0 + 0];
        float v1 = red[1][0] + red[1][1] + red[1][2] + red[1][3] + b[3 * i0 + 1];
        float v2 = red[2][0] + red[2][1] + red[2][2] + red[2][3] + b[3 * i0 + 2];
        shift[i0] = v0;
        scale[i0] = v1;
        gate[i0]  = v2;
    }
}

// One block per sequence row. Two-phase: load x into regs (3 float4/thread),
// sum+sumsq reduce, then fused normalize*scale+shift write.
__global__ __launch_bounds__(256) void ln_affine_kernel(
    const float* __restrict__ x, const float* __restrict__ shift,
    const float* __restrict__ scale, float* __restrict__ out)
{
    const int row = blockIdx.x;
    const int t = threadIdx.x;
    const float4* x4 = (const float4*)(x + (size_t)row * DIM);
    float4* o4 = (float4*)(out + (size_t)row * DIM);
    const float4* sc4 = (const float4*)scale;
    const float4* sh4 = (const float4*)shift;

    float4 v[3];
    float sum = 0.f, sq = 0.f;
    #pragma unroll
    for (int k = 0; k < 3; ++k) {
        v[k] = x4[t + k * 256];
        sum += v[k].x + v[k].y + v[k].z + v[k].w;
        sq  += v[k].x * v[k].x + v[k].y * v[k].y + v[k].z * v[k].z + v[k].w * v[k].w;
    }

    #pragma unroll
    for (int off = 32; off > 0; off >>= 1) {
        sum += __shfl_down(sum, off, 64);
        sq  += __shfl_down(sq,  off, 64);
    }
    __shared__ float rsum[4], rsq[4];
    __shared__ float mean_s, rstd_s;
    const int wave = t >> 6;
    if ((t & 63) == 0) { rsum[wave] = sum; rsq[wave] = sq; }
    __syncthreads();
    if (t == 0) {
        float S = rsum[0] + rsum[1] + rsum[2] + rsum[3];
        float Q = rsq[0] + rsq[1] + rsq[2] + rsq[3];
        float mean = S * (1.0f / DIM);
        float var = Q * (1.0f / DIM) - mean * mean;
        mean_s = mean;
        rstd_s = rsqrtf(var + 1e-6f);
    }
    __syncthreads();
    const float mean = mean_s, rstd = rstd_s;

    #pragma unroll
    for (int k = 0; k < 3; ++k) {
        int i = t + k * 256;
        float4 sc = sc4[i];
        float4 sh = sh4[i];
        float4 r;
        r.x = (v[k].x - mean) * rstd * sc.x + sh.x;
        r.y = (v[k].y - mean) * rstd * sc.y + sh.y;
        r.z = (v[k].z - mean) * rstd * sc.z + sh.z;
        r.w = (v[k].w - mean) * rstd * sc.w + sh.w;
        o4[i] = r;
    }
}

extern "C" void kernel_launch(void* const* d_in, const int* in_sizes, int n_in,
                              void* d_out, int out_size, void* d_ws, size_t ws_size,
                              hipStream_t stream) {
    const float* x   = (const float*)d_in[0];  // [1, 8192, 3072]
    const float* emb = (const float*)d_in[1];  // [1, 3072]
    const float* W   = (const float*)d_in[2];  // [9216, 3072]
    const float* b   = (const float*)d_in[3];  // [9216]
    float* out  = (float*)d_out;                       // [1,8192,3072] flat
    float* gate = out + (size_t)SEQ * DIM;             // [1,3072] appended
    float* shift = (float*)d_ws;                       // [3072]
    float* scale = shift + DIM;                        // [3072]

    gemv3_kernel<<<DIM, 256, 0, stream>>>(emb, W, b, shift, scale, gate);
    ln_affine_kernel<<<SEQ, 256, 0, stream>>>(x, shift, scale, out);
}